// Round 4
// baseline (202.331 us; speedup 1.0000x reference)
//
#include <hip/hip_runtime.h>

// CloudCrop fused MFMA kernel, round 4: 3 blocks/CU (LDS ~49KB), direct
// global A-frags from pre-transposed upT (f16), reg-softmax with partials
// exchange, colsum via ones-MFMA. B=2,S=1024,N=10000,C=128,NS=64,hidden=256.

typedef _Float16 f16;
typedef _Float16 f16x8 __attribute__((ext_vector_type(8)));
typedef _Float16 f16x4v __attribute__((ext_vector_type(4)));
typedef float f32x4 __attribute__((ext_vector_type(4)));

constexpr int Nn = 10000;
constexpr float RAD2 = 0.05f * 0.05f;
constexpr float HMINf = -0.02f, HMAXf = 0.02f;
constexpr float INVV = 0.99999500003749968747f; // 1/sqrt(1+1e-5)

// ws layout:
//   [0, 376832): 368 weight fragment tiles (1KB each: [64 lanes][8 f16])
//     WA 0..79 (mlp, K 131->160; k 0..127=feat, 128..130=xyz), WQ 80..111,
//     WV 112..239, WT 240..367
//   [376832, +5.12MB): upT (B, N, 128) f16
#define NTILES 368
#define UPT_OFF 376832

__device__ __forceinline__ int swzb(int row, int colbyte) {
    return colbyte ^ ((row & 7) << 4);
}

__global__ void prep_kernel(const float* __restrict__ mlp_w,
                            const float* __restrict__ qk_w,
                            const float* __restrict__ v_w,
                            const float* __restrict__ t_w,
                            const float* __restrict__ up,
                            unsigned char* __restrict__ ws) {
    const int blk = blockIdx.x;
    if (blk < 92) {
        const int tid = blk * 256 + threadIdx.x;  // < 368*64
        const int tile = tid >> 6, lane = tid & 63;
        const int ln = lane & 15, kg = lane >> 4;
        f16x8 v;
        if (tile < 80) {
            const int kc = tile / 16, ct = tile % 16;
            const int n = ct * 16 + ln, kb = kc * 32 + kg * 8;
            #pragma unroll
            for (int i = 0; i < 8; ++i) {
                const int k = kb + i;
                float x = (k < 128) ? mlp_w[n * 131 + 3 + k]
                        : ((k < 131) ? mlp_w[n * 131 + (k - 128)] : 0.f);
                v[i] = (f16)x;
            }
        } else if (tile < 112) {
            const int t2 = tile - 80; const int kc = t2 >> 2, ct = t2 & 3;
            const int n = ct * 16 + ln, kb = kc * 32 + kg * 8;
            #pragma unroll
            for (int i = 0; i < 8; ++i) v[i] = (f16)qk_w[n * 256 + kb + i];
        } else if (tile < 240) {
            const int t2 = tile - 112; const int kc = t2 >> 4, ct = t2 & 15;
            const int n = ct * 16 + ln, kb = kc * 32 + kg * 8;
            #pragma unroll
            for (int i = 0; i < 8; ++i) v[i] = (f16)v_w[n * 256 + kb + i];
        } else {
            const int t2 = tile - 240; const int kc = t2 >> 4, ct = t2 & 15;
            const int n = ct * 16 + ln, kb = kc * 32 + kg * 8;
            #pragma unroll
            for (int i = 0; i < 8; ++i) v[i] = (f16)t_w[n * 256 + kb + i];
        }
        *(f16x8*)(ws + (size_t)tid * 16) = v;
    } else {
        // upT transpose: block covers 64 points of one batch
        const int bidx = blk - 92;                 // 0..313
        const int b = bidx / 157;
        const int n0 = (bidx % 157) * 64;
        const int ln = threadIdx.x & 63;
        const int cw = threadIdx.x >> 6;           // 0..3
        const int n = n0 + ln;
        if (n < Nn) {
            f16* dst = (f16*)(ws + UPT_OFF) + ((size_t)b * Nn + n) * 128;
            const float* upb = up + (size_t)b * 128 * Nn;
            #pragma unroll
            for (int i = 0; i < 32; ++i) {
                const int c = cw + i * 4;          // coalesced read over n
                dst[c] = (f16)upb[(size_t)c * Nn + n];
            }
        }
    }
}

__launch_bounds__(256, 3)
__global__ void cloudcrop_mfma(
    const float* __restrict__ seed,  // (B,S,3)
    const float* __restrict__ pc,    // (B,N,3)
    const float* __restrict__ rot,   // (B,S,3,3)
    const float* __restrict__ mlp_b,
    const float* __restrict__ bn1g,
    const float* __restrict__ bn1b,
    const float* __restrict__ v_b,
    const float* __restrict__ t_b,
    const float* __restrict__ bn2g,
    const float* __restrict__ bn2b,
    const unsigned char* __restrict__ ws,
    float* __restrict__ out)         // (B,256,S) f32
{
    __shared__ __align__(16) unsigned char s_x[64 * 512]; // X [64][256] f16 swz; Y in-place later
    __shared__ __align__(16) unsigned char s_q[8192];     // Q then attT [64][64] f16 swz (s128B)
    __shared__ __align__(16) unsigned char s_m[8448];     // cand(0..4112) | xyz(4352..8448) | partials(0..2048) | bounce(0..8192)
    __shared__ int idx_s[64];
    __shared__ int cand_n4[4];

    int*   cand_i = (int*)s_m;              // [4][64]
    float* cand_x = (float*)(s_m + 1024);
    float* cand_y = (float*)(s_m + 2048);
    float* cand_z = (float*)(s_m + 3072);
    f16*   s_xyz  = (f16*)(s_m + 4352);     // [64][32] plain
    float* s_part = (float*)s_m;            // [64][4] float2 (pmax,psum)

    const int grp = blockIdx.x;
    const int bb = grp >> 10;
    const int s  = grp & 1023;
    const int t  = threadIdx.x;
    const int lane = t & 63;
    const int w    = t >> 6;
    const int ln   = lane & 15;
    const int kg   = lane >> 4;
    const int kg16 = kg * 16;
    const int g4   = kg * 4;

    // ---------- Phase 0: selection scan, 4 waves x 2500 pts -----------------
    {
        const float sx = seed[grp*3+0], sy = seed[grp*3+1], sz = seed[grp*3+2];
        const float R0 = rot[grp*9+0], R1 = rot[grp*9+1], R2 = rot[grp*9+2];
        const float R3 = rot[grp*9+3], R4 = rot[grp*9+4], R5 = rot[grp*9+5];
        const float R6 = rot[grp*9+6], R7 = rot[grp*9+7], R8 = rot[grp*9+8];
        int count = 0;
        const int lo = w * 2500, hi = lo + 2500;
        for (int base = lo; base < hi; base += 64) {
            const int n = base + lane;
            bool m = false; float rx = 0.f, ry = 0.f, rz = 0.f;
            if (n < hi) {
                const float px = pc[(bb*Nn + n)*3+0] - sx;
                const float py = pc[(bb*Nn + n)*3+1] - sy;
                const float pz = pc[(bb*Nn + n)*3+2] - sz;
                rx = px*R0 + py*R3 + pz*R6;
                ry = px*R1 + py*R4 + pz*R7;
                rz = px*R2 + py*R5 + pz*R8;
                m = (ry*ry + rz*rz < RAD2) && (rx > HMINf) && (rx < HMAXf);
            }
            const unsigned long long bal = __ballot(m);
            const int below = __popcll(bal & ((1ull << lane) - 1ull));
            const int pos = count + below;
            if (m && pos < 64) {
                cand_i[w*64 + pos] = n;
                cand_x[w*64 + pos] = rx; cand_y[w*64 + pos] = ry; cand_z[w*64 + pos] = rz;
            }
            count += __popcll(bal);
        }
        if (lane == 0) cand_n4[w] = count < 64 ? count : 64;
    }
    __syncthreads();

    // ---------- Merge (ordered) -> idx_s + xyz tile -------------------------
    if (t < 64) {
        const int c0 = cand_n4[0], c1 = cand_n4[1], c2 = cand_n4[2], c3 = cand_n4[3];
        const int o1 = c0, o2 = c0 + c1, o3 = o2 + c2;
        int total = o3 + c3; if (total > 64) total = 64;
        int myi; float rx, ry, rz;
        if (total > 0) {
            const int pp = (t < total) ? t : 0;
            int sw_, sq;
            if      (pp >= o3) { sw_ = 3; sq = pp - o3; }
            else if (pp >= o2) { sw_ = 2; sq = pp - o2; }
            else if (pp >= o1) { sw_ = 1; sq = pp - o1; }
            else               { sw_ = 0; sq = pp; }
            myi = cand_i[sw_*64 + sq];
            rx = cand_x[sw_*64 + sq]; ry = cand_y[sw_*64 + sq]; rz = cand_z[sw_*64 + sq];
        } else {
            const float sx = seed[grp*3+0], sy = seed[grp*3+1], sz = seed[grp*3+2];
            const float px = pc[(bb*Nn)*3+0] - sx;
            const float py = pc[(bb*Nn)*3+1] - sy;
            const float pz = pc[(bb*Nn)*3+2] - sz;
            rx = px*rot[grp*9+0] + py*rot[grp*9+3] + pz*rot[grp*9+6];
            ry = px*rot[grp*9+1] + py*rot[grp*9+4] + pz*rot[grp*9+7];
            rz = px*rot[grp*9+2] + py*rot[grp*9+5] + pz*rot[grp*9+8];
            myi = 0;
        }
        idx_s[t] = myi;
        f16x8 z0 = {};
        z0[0] = (f16)rx; z0[1] = (f16)ry; z0[2] = (f16)rz;
        f16x8 zz = {};
        f16x8* xr = (f16x8*)(s_xyz + t * 32);
        xr[0] = z0; xr[1] = zz; xr[2] = zz; xr[3] = zz;
    }
    __syncthreads();

    // ---------- Phase A: H = [feat|xyz](64x160) @ WA -> X (+bias,BN1,ReLU) --
    {
        int idxr[4];
        #pragma unroll
        for (int rt = 0; rt < 4; ++rt) idxr[rt] = idx_s[rt*16 + ln];
        const f16* upTb = (const f16*)(ws + UPT_OFF) + (size_t)bb * Nn * 128;

        f32x4 acc[4][4] = {};
        #pragma unroll
        for (int kc = 0; kc < 4; ++kc) {
            f16x8 a[4];
            #pragma unroll
            for (int rt = 0; rt < 4; ++rt)
                a[rt] = *(const f16x8*)(upTb + (size_t)idxr[rt]*128 + kc*32 + kg*8);
            #pragma unroll
            for (int j = 0; j < 4; ++j) {
                const f16x8 bf = *(const f16x8*)(ws + (size_t)(kc*16 + 4*w + j)*1024 + lane*16);
                #pragma unroll
                for (int rt = 0; rt < 4; ++rt)
                    acc[rt][j] = __builtin_amdgcn_mfma_f32_16x16x32_f16(a[rt], bf, acc[rt][j], 0, 0, 0);
            }
        }
        {   // kc = 4: xyz tile from LDS
            f16x8 a[4];
            #pragma unroll
            for (int rt = 0; rt < 4; ++rt)
                a[rt] = *(const f16x8*)(s_xyz + (rt*16 + ln)*32 + kg*8);
            #pragma unroll
            for (int j = 0; j < 4; ++j) {
                const f16x8 bf = *(const f16x8*)(ws + (size_t)(64 + 4*w + j)*1024 + lane*16);
                #pragma unroll
                for (int rt = 0; rt < 4; ++rt)
                    acc[rt][j] = __builtin_amdgcn_mfma_f32_16x16x32_f16(a[rt], bf, acc[rt][j], 0, 0, 0);
            }
        }
        #pragma unroll
        for (int j = 0; j < 4; ++j) {
            const int col = (4*w + j)*16 + ln;
            const float mb = mlp_b[col], g1 = bn1g[col]*INVV, b1 = bn1b[col];
            #pragma unroll
            for (int rt = 0; rt < 4; ++rt)
                #pragma unroll
                for (int r = 0; r < 4; ++r) {
                    const int row = rt*16 + g4 + r;
                    const float h = fmaxf((acc[rt][j][r] + mb)*g1 + b1, 0.f);
                    *(f16*)(s_x + row*512 + swzb(row, col*2)) = (f16)h;
                }
        }
    }
    __syncthreads();

    // ---------- Phase B: Q = X @ WQ (64x64), wave w -> coltile w ------------
    {
        f32x4 accq[4] = {};
        #pragma unroll
        for (int kc = 0; kc < 8; ++kc) {
            const f16x8 bf = *(const f16x8*)(ws + (size_t)(80 + kc*4 + w)*1024 + lane*16);
            #pragma unroll
            for (int rt = 0; rt < 4; ++rt) {
                const int row = rt*16 + ln;
                const f16x8 a = *(const f16x8*)(s_x + row*512 + swzb(row, kc*64 + kg16));
                accq[rt] = __builtin_amdgcn_mfma_f32_16x16x32_f16(a, bf, accq[rt], 0, 0, 0);
            }
        }
        const int col = w*16 + ln;
        #pragma unroll
        for (int rt = 0; rt < 4; ++rt)
            #pragma unroll
            for (int r = 0; r < 4; ++r) {
                const int row = rt*16 + g4 + r;
                *(f16*)(s_q + row*128 + swzb(row, col*2)) = (f16)accq[rt][r];
            }
    }
    __syncthreads();

    // ---------- Phase C: S = Q @ Q^T; reg-softmax with partial exchange -----
    {
        f32x4 accs[4] = {};
        #pragma unroll
        for (int kc = 0; kc < 2; ++kc) {
            const int rowb = w*16 + ln;
            const f16x8 bf = *(const f16x8*)(s_q + rowb*128 + swzb(rowb, kc*64 + kg16));
            #pragma unroll
            for (int rt = 0; rt < 4; ++rt) {
                const int row = rt*16 + ln;
                const f16x8 a = *(const f16x8*)(s_q + row*128 + swzb(row, kc*64 + kg16));
                accs[rt] = __builtin_amdgcn_mfma_f32_16x16x32_f16(a, bf, accs[rt], 0, 0, 0);
            }
        }
        // per-(rt,r): 16-lane partial max + sum of exp
        float pm[4][4];
        #pragma unroll
        for (int rt = 0; rt < 4; ++rt)
            #pragma unroll
            for (int r = 0; r < 4; ++r) {
                float v = accs[rt][r];
                float mx = fmaxf(v, __shfl_xor(v, 1));
                mx = fmaxf(mx, __shfl_xor(mx, 2));
                mx = fmaxf(mx, __shfl_xor(mx, 4));
                mx = fmaxf(mx, __shfl_xor(mx, 8));
                pm[rt][r] = mx;
                const float e = __expf(v - mx);
                accs[rt][r] = e;
                float sm = e + __shfl_xor(e, 1);
                sm += __shfl_xor(sm, 2);
                sm += __shfl_xor(sm, 4);
                sm += __shfl_xor(sm, 8);
                if (ln == 0) {
                    const int row = rt*16 + g4 + r;
                    s_part[row*8 + w*2 + 0] = mx;
                    s_part[row*8 + w*2 + 1] = sm;
                }
            }
        __syncthreads();
        // finalize: full max/denominator, write attT f16
        const int arow = w*16 + ln;
        #pragma unroll
        for (int rt = 0; rt < 4; ++rt) {
            f16x4v pk;
            #pragma unroll
            for (int r = 0; r < 4; ++r) {
                const int row = rt*16 + g4 + r;
                const f32x4 pa = *(const f32x4*)(s_part + row*8);
                const f32x4 pb = *(const f32x4*)(s_part + row*8 + 4);
                const float fm = fmaxf(fmaxf(pa.x, pa.z), fmaxf(pb.x, pb.z));
                const float den = pa.y*__expf(pa.x - fm) + pa.w*__expf(pa.z - fm)
                                + pb.y*__expf(pb.x - fm) + pb.w*__expf(pb.z - fm);
                const float sc = __expf(pm[rt][r] - fm) / den;
                pk[r] = (f16)(accs[rt][r] * sc);
            }
            // attT[j = arow][i = rt*16+g4+0..3]
            *(f16x4v*)(s_q + arow*128 + swzb(arow, (rt*16 + g4)*2)) = pk;
        }
    }
    __syncthreads();

    // ---------- Phase D: V=X@WV+vb, bounce transpose, XR=attT@V, colsum -----
    f32x4 accr[4][4] = {};
    f32x4 accONE[4] = {};
    {
        f16x8 a2[2][4];
        #pragma unroll
        for (int kc = 0; kc < 2; ++kc)
            #pragma unroll
            for (int rt = 0; rt < 4; ++rt) {
                const int row = rt*16 + ln;
                a2[kc][rt] = *(const f16x8*)(s_q + row*128 + swzb(row, kc*64 + kg16));
            }
        // colsum_j = sum_k attT[j][k] via ones-MFMA (matches accr C/D layout)
        f16x8 onef;
        #pragma unroll
        for (int i = 0; i < 8; ++i) onef[i] = (f16)1.0f;
        #pragma unroll
        for (int kc = 0; kc < 2; ++kc)
            #pragma unroll
            for (int rt = 0; rt < 4; ++rt)
                accONE[rt] = __builtin_amdgcn_mfma_f32_16x16x32_f16(a2[kc][rt], onef, accONE[rt], 0, 0, 0);

        f32x4 accv[4][4] = {};
        #pragma unroll 2
        for (int kc = 0; kc < 8; ++kc) {
            f16x8 a[4];
            #pragma unroll
            for (int rt = 0; rt < 4; ++rt) {
                const int row = rt*16 + ln;
                a[rt] = *(const f16x8*)(s_x + row*512 + swzb(row, kc*64 + kg16));
            }
            #pragma unroll
            for (int j = 0; j < 4; ++j) {
                const f16x8 bf = *(const f16x8*)(ws + (size_t)(112 + kc*16 + 4*w + j)*1024 + lane*16);
                #pragma unroll
                for (int rt = 0; rt < 4; ++rt)
                    accv[rt][j] = __builtin_amdgcn_mfma_f32_16x16x32_f16(a[rt], bf, accv[rt][j], 0, 0, 0);
            }
        }
        unsigned char* bw = s_m + w*2048;  // per-wave bounce [16 ch][64 samples]
        #pragma unroll
        for (int j = 0; j < 4; ++j) {
            const float vb = v_b[(4*w + j)*16 + ln];
            #pragma unroll
            for (int rt = 0; rt < 4; ++rt)
                #pragma unroll
                for (int r = 0; r < 4; ++r) {
                    const int sr = rt*16 + g4 + r;
                    *(f16*)(bw + ln*128 + ((sr*2) ^ ((ln & 7) << 4))) = (f16)(accv[rt][j][r] + vb);
                }
            asm volatile("s_waitcnt lgkmcnt(0)" ::: "memory");
            #pragma unroll
            for (int kc = 0; kc < 2; ++kc) {
                const f16x8 bf = *(const f16x8*)(bw + ln*128 + ((kc*64 + kg16) ^ ((ln & 7) << 4)));
                #pragma unroll
                for (int rt = 0; rt < 4; ++rt)
                    accr[rt][j] = __builtin_amdgcn_mfma_f32_16x16x32_f16(a2[kc][rt], bf, accr[rt][j], 0, 0, 0);
            }
            asm volatile("" ::: "memory");
        }
    }
    __syncthreads();  // all waves' X reads done before Y overwrite

    // ---------- D-epilogue: Y = X - XR/colsum (in-place), keep X in regs ----
    f16x4v xsave[4][4];
    #pragma unroll
    for (int j = 0; j < 4; ++j) {
        const int col = (4*w + j)*16 + ln;
        #pragma unroll
        for (int rt = 0; rt < 4; ++rt) {
            f16x4v xs4;
            #pragma unroll
            for (int r = 0; r < 4; ++r) {
                const int row = rt*16 + g4 + r;
                const f16 xv = *(const f16*)(s_x + row*512 + swzb(row, col*2));
                xs4[r] = xv;
                const float yv = (float)xv - accr[rt][j][r] / (1e-9f + accONE[rt][r]);
                *(f16*)(s_x + row*512 + swzb(row, col*2)) = (f16)yv;
            }
            xsave[j][rt] = xs4;
        }
    }
    __syncthreads();

    // ---------- Phase E: T = Y @ WT + t_b; out = maxpool(X + relu(BN2)) -----
    {
        f32x4 acct[4][4] = {};
        #pragma unroll 2
        for (int kc = 0; kc < 8; ++kc) {
            f16x8 a[4];
            #pragma unroll
            for (int rt = 0; rt < 4; ++rt) {
                const int row = rt*16 + ln;
                a[rt] = *(const f16x8*)(s_x + row*512 + swzb(row, kc*64 + kg16));  // Y
            }
            #pragma unroll
            for (int j = 0; j < 4; ++j) {
                const f16x8 bf = *(const f16x8*)(ws + (size_t)(240 + kc*16 + 4*w + j)*1024 + lane*16);
                #pragma unroll
                for (int rt = 0; rt < 4; ++rt)
                    acct[rt][j] = __builtin_amdgcn_mfma_f32_16x16x32_f16(a[rt], bf, acct[rt][j], 0, 0, 0);
            }
        }
        #pragma unroll
        for (int j = 0; j < 4; ++j) {
            const int col = (4*w + j)*16 + ln;
            const float tb = t_b[col], g2 = bn2g[col]*INVV, b2 = bn2b[col];
            float m = -3.4e38f;
            #pragma unroll
            for (int rt = 0; rt < 4; ++rt)
                #pragma unroll
                for (int r = 0; r < 4; ++r) {
                    const float tv = acct[rt][j][r] + tb;
                    const float rl = fmaxf(tv*g2 + b2, 0.f);
                    const float xv = (float)xsave[j][rt][r];
                    m = fmaxf(m, xv + rl);
                }
            m = fmaxf(m, __shfl_xor(m, 16));
            m = fmaxf(m, __shfl_xor(m, 32));
            if (kg == 0)
                out[((size_t)bb*256 + col)*1024 + s] = m;
        }
    }
}

extern "C" void kernel_launch(void* const* d_in, const int* in_sizes, int n_in,
                              void* d_out, int out_size, void* d_ws, size_t ws_size,
                              hipStream_t stream) {
    (void)in_sizes; (void)n_in; (void)out_size; (void)ws_size;
    unsigned char* ws = (unsigned char*)d_ws;
    prep_kernel<<<92 + 314, 256, 0, stream>>>(
        (const float*)d_in[4],   // mlp_w
        (const float*)d_in[8],   // qk_w
        (const float*)d_in[9],   // v_w
        (const float*)d_in[11],  // t_w
        (const float*)d_in[3],   // up_feature
        ws);
    cloudcrop_mfma<<<2048, 256, 0, stream>>>(
        (const float*)d_in[0],   // seed_xyz
        (const float*)d_in[1],   // pointcloud
        (const float*)d_in[2],   // vp_rot
        (const float*)d_in[5],   // mlp_b
        (const float*)d_in[6],   // bn1_g
        (const float*)d_in[7],   // bn1_b
        (const float*)d_in[10],  // v_b
        (const float*)d_in[12],  // t_b
        (const float*)d_in[13],  // bn2_g
        (const float*)d_in[14],  // bn2_b
        ws,
        (float*)d_out);
}

// Round 5
// 161.907 us; speedup vs baseline: 1.2497x; 1.2497x over previous
//
#include <hip/hip_runtime.h>

// CloudCrop fused MFMA kernel, round 5: spill-free register schedule
// (per-j phase D), coalesced prep transpose, 2x-unrolled selection.
// B=2,S=1024,N=10000,C=128,NS=64,hidden=256. 3 blocks/CU (LDS ~49KB).

typedef _Float16 f16;
typedef _Float16 f16x8 __attribute__((ext_vector_type(8)));
typedef _Float16 f16x4v __attribute__((ext_vector_type(4)));
typedef float f32x4 __attribute__((ext_vector_type(4)));

constexpr int Nn = 10000;
constexpr float RAD2 = 0.05f * 0.05f;
constexpr float HMINf = -0.02f, HMAXf = 0.02f;
constexpr float INVV = 0.99999500003749968747f; // 1/sqrt(1+1e-5)

// ws layout:
//   [0, 376832): 368 weight fragment tiles (1KB each: [64 lanes][8 f16])
//     WA 0..79 (mlp, K 131->160; k 0..127=feat, 128..130=xyz), WQ 80..111,
//     WV 112..239, WT 240..367
//   [376832, +5.12MB): upT (B, N, 128) f16
#define NTILES 368
#define UPT_OFF 376832

__device__ __forceinline__ int swzb(int row, int colbyte) {
    return colbyte ^ ((row & 7) << 4);
}

__global__ void prep_kernel(const float* __restrict__ mlp_w,
                            const float* __restrict__ qk_w,
                            const float* __restrict__ v_w,
                            const float* __restrict__ t_w,
                            const float* __restrict__ up,
                            unsigned char* __restrict__ ws) {
    const int blk = blockIdx.x;
    if (blk < 92) {
        const int tid = blk * 256 + threadIdx.x;  // < 368*64
        const int tile = tid >> 6, lane = tid & 63;
        const int ln = lane & 15, kg = lane >> 4;
        f16x8 v;
        if (tile < 80) {
            const int kc = tile / 16, ct = tile % 16;
            const int n = ct * 16 + ln, kb = kc * 32 + kg * 8;
            #pragma unroll
            for (int i = 0; i < 8; ++i) {
                const int k = kb + i;
                float x = (k < 128) ? mlp_w[n * 131 + 3 + k]
                        : ((k < 131) ? mlp_w[n * 131 + (k - 128)] : 0.f);
                v[i] = (f16)x;
            }
        } else if (tile < 112) {
            const int t2 = tile - 80; const int kc = t2 >> 2, ct = t2 & 3;
            const int n = ct * 16 + ln, kb = kc * 32 + kg * 8;
            #pragma unroll
            for (int i = 0; i < 8; ++i) v[i] = (f16)qk_w[n * 256 + kb + i];
        } else if (tile < 240) {
            const int t2 = tile - 112; const int kc = t2 >> 4, ct = t2 & 15;
            const int n = ct * 16 + ln, kb = kc * 32 + kg * 8;
            #pragma unroll
            for (int i = 0; i < 8; ++i) v[i] = (f16)v_w[n * 256 + kb + i];
        } else {
            const int t2 = tile - 240; const int kc = t2 >> 4, ct = t2 & 15;
            const int n = ct * 16 + ln, kb = kc * 32 + kg * 8;
            #pragma unroll
            for (int i = 0; i < 8; ++i) v[i] = (f16)t_w[n * 256 + kb + i];
        }
        *(f16x8*)(ws + (size_t)tid * 16) = v;
    } else {
        // upT transpose via LDS tile: coalesced reads AND writes
        __shared__ f16 tile[64 * 136];             // pad 128->136 (bank spread)
        const int bidx = blk - 92;                 // 0..313
        const int b = bidx / 157;
        const int n0 = (bidx % 157) * 64;
        const int lane = threadIdx.x & 63;
        const int cw = threadIdx.x >> 6;           // 0..3
        const int n = n0 + lane;
        const float* upb = up + (size_t)b * 128 * Nn;
        #pragma unroll
        for (int i = 0; i < 32; ++i) {
            const int c = cw * 32 + i;
            const float x = (n < Nn) ? upb[(size_t)c * Nn + n] : 0.f;
            tile[lane * 136 + c] = (f16)x;         // read coalesced over lane
        }
        __syncthreads();
        f16* dst = (f16*)(ws + UPT_OFF) + (size_t)b * Nn * 128;
        #pragma unroll
        for (int p = 0; p < 4; ++p) {
            const int flat8 = threadIdx.x + p * 256;   // 0..1023 chunks of 8
            const int row = flat8 >> 4;
            const int c = (flat8 & 15) * 8;
            if (n0 + row < Nn)
                *(f16x8*)(dst + ((size_t)(n0 + row)) * 128 + c) =
                    *(const f16x8*)(tile + row * 136 + c);
        }
    }
}

__launch_bounds__(256, 3)
__global__ void cloudcrop_mfma(
    const float* __restrict__ seed,  // (B,S,3)
    const float* __restrict__ pc,    // (B,N,3)
    const float* __restrict__ rot,   // (B,S,3,3)
    const float* __restrict__ mlp_b,
    const float* __restrict__ bn1g,
    const float* __restrict__ bn1b,
    const float* __restrict__ v_b,
    const float* __restrict__ t_b,
    const float* __restrict__ bn2g,
    const float* __restrict__ bn2b,
    const unsigned char* __restrict__ ws,
    float* __restrict__ out)         // (B,256,S) f32
{
    __shared__ __align__(16) unsigned char s_x[64 * 512]; // X [64][256] f16 swz; Y in-place later
    __shared__ __align__(16) unsigned char s_q[8192];     // Q then attT [64][64] f16 swz (s128B)
    __shared__ __align__(16) unsigned char s_m[8448];     // cand | xyz | partials | bounce
    __shared__ int idx_s[64];
    __shared__ int cand_n4[4];

    int*   cand_i = (int*)s_m;              // [4][64]
    float* cand_x = (float*)(s_m + 1024);
    float* cand_y = (float*)(s_m + 2048);
    float* cand_z = (float*)(s_m + 3072);
    f16*   s_xyz  = (f16*)(s_m + 4352);     // [64][32] plain
    float* s_part = (float*)s_m;            // [64][8] (pmax,psum)x4 waves

    const int grp = blockIdx.x;
    const int bb = grp >> 10;
    const int s  = grp & 1023;
    const int t  = threadIdx.x;
    const int lane = t & 63;
    const int w    = t >> 6;
    const int ln   = lane & 15;
    const int kg   = lane >> 4;
    const int kg16 = kg * 16;
    const int g4   = kg * 4;

    // ---------- Phase 0: selection scan, 4 waves x 2500 pts, 2x unroll ------
    {
        const float sx = seed[grp*3+0], sy = seed[grp*3+1], sz = seed[grp*3+2];
        const float R0 = rot[grp*9+0], R1 = rot[grp*9+1], R2 = rot[grp*9+2];
        const float R3 = rot[grp*9+3], R4 = rot[grp*9+4], R5 = rot[grp*9+5];
        const float R6 = rot[grp*9+6], R7 = rot[grp*9+7], R8 = rot[grp*9+8];
        const unsigned long long lmask = (1ull << lane) - 1ull;
        int count = 0;
        const int lo = w * 2500, hi = lo + 2500;
        for (int base = lo; base < hi; base += 128) {
            const int n0i = base + lane, n1i = base + 64 + lane;
            bool m0 = false, m1 = false;
            float rx0=0.f, ry0=0.f, rz0=0.f, rx1=0.f, ry1=0.f, rz1=0.f;
            if (n0i < hi) {
                const float px = pc[(bb*Nn + n0i)*3+0] - sx;
                const float py = pc[(bb*Nn + n0i)*3+1] - sy;
                const float pz = pc[(bb*Nn + n0i)*3+2] - sz;
                rx0 = px*R0 + py*R3 + pz*R6;
                ry0 = px*R1 + py*R4 + pz*R7;
                rz0 = px*R2 + py*R5 + pz*R8;
                m0 = (ry0*ry0 + rz0*rz0 < RAD2) && (rx0 > HMINf) && (rx0 < HMAXf);
            }
            if (n1i < hi) {
                const float px = pc[(bb*Nn + n1i)*3+0] - sx;
                const float py = pc[(bb*Nn + n1i)*3+1] - sy;
                const float pz = pc[(bb*Nn + n1i)*3+2] - sz;
                rx1 = px*R0 + py*R3 + pz*R6;
                ry1 = px*R1 + py*R4 + pz*R7;
                rz1 = px*R2 + py*R5 + pz*R8;
                m1 = (ry1*ry1 + rz1*rz1 < RAD2) && (rx1 > HMINf) && (rx1 < HMAXf);
            }
            const unsigned long long bal0 = __ballot(m0);
            const unsigned long long bal1 = __ballot(m1);
            const int c0 = __popcll(bal0);
            const int pos0 = count + __popcll(bal0 & lmask);
            const int pos1 = count + c0 + __popcll(bal1 & lmask);
            if (m0 && pos0 < 64) {
                cand_i[w*64 + pos0] = n0i;
                cand_x[w*64 + pos0] = rx0; cand_y[w*64 + pos0] = ry0; cand_z[w*64 + pos0] = rz0;
            }
            if (m1 && pos1 < 64) {
                cand_i[w*64 + pos1] = n1i;
                cand_x[w*64 + pos1] = rx1; cand_y[w*64 + pos1] = ry1; cand_z[w*64 + pos1] = rz1;
            }
            count += c0 + __popcll(bal1);
        }
        if (lane == 0) cand_n4[w] = count < 64 ? count : 64;
    }
    __syncthreads();

    // ---------- Merge (ordered) -> idx_s + xyz tile -------------------------
    if (t < 64) {
        const int c0 = cand_n4[0], c1 = cand_n4[1], c2 = cand_n4[2], c3 = cand_n4[3];
        const int o1 = c0, o2 = c0 + c1, o3 = o2 + c2;
        int total = o3 + c3; if (total > 64) total = 64;
        int myi; float rx, ry, rz;
        if (total > 0) {
            const int pp = (t < total) ? t : 0;
            int sw_, sq;
            if      (pp >= o3) { sw_ = 3; sq = pp - o3; }
            else if (pp >= o2) { sw_ = 2; sq = pp - o2; }
            else if (pp >= o1) { sw_ = 1; sq = pp - o1; }
            else               { sw_ = 0; sq = pp; }
            myi = cand_i[sw_*64 + sq];
            rx = cand_x[sw_*64 + sq]; ry = cand_y[sw_*64 + sq]; rz = cand_z[sw_*64 + sq];
        } else {
            const float sx = seed[grp*3+0], sy = seed[grp*3+1], sz = seed[grp*3+2];
            const float px = pc[(bb*Nn)*3+0] - sx;
            const float py = pc[(bb*Nn)*3+1] - sy;
            const float pz = pc[(bb*Nn)*3+2] - sz;
            rx = px*rot[grp*9+0] + py*rot[grp*9+3] + pz*rot[grp*9+6];
            ry = px*rot[grp*9+1] + py*rot[grp*9+4] + pz*rot[grp*9+7];
            rz = px*rot[grp*9+2] + py*rot[grp*9+5] + pz*rot[grp*9+8];
            myi = 0;
        }
        idx_s[t] = myi;
        f16x8 z0 = {};
        z0[0] = (f16)rx; z0[1] = (f16)ry; z0[2] = (f16)rz;
        f16x8 zz = {};
        f16x8* xr = (f16x8*)(s_xyz + t * 32);
        xr[0] = z0; xr[1] = zz; xr[2] = zz; xr[3] = zz;
    }
    __syncthreads();

    // ---------- Phase A: H = [feat|xyz](64x160) @ WA -> X (+bias,BN1,ReLU) --
    {
        int idxr[4];
        #pragma unroll
        for (int rt = 0; rt < 4; ++rt) idxr[rt] = idx_s[rt*16 + ln];
        const f16* upTb = (const f16*)(ws + UPT_OFF) + (size_t)bb * Nn * 128;

        f32x4 acc[4][4] = {};
        #pragma unroll
        for (int kc = 0; kc < 4; ++kc) {
            f16x8 a[4];
            #pragma unroll
            for (int rt = 0; rt < 4; ++rt)
                a[rt] = *(const f16x8*)(upTb + (size_t)idxr[rt]*128 + kc*32 + kg*8);
            #pragma unroll
            for (int j = 0; j < 4; ++j) {
                const f16x8 bf = *(const f16x8*)(ws + (size_t)(kc*16 + 4*w + j)*1024 + lane*16);
                #pragma unroll
                for (int rt = 0; rt < 4; ++rt)
                    acc[rt][j] = __builtin_amdgcn_mfma_f32_16x16x32_f16(a[rt], bf, acc[rt][j], 0, 0, 0);
            }
        }
        {   // kc = 4: xyz tile from LDS
            f16x8 a[4];
            #pragma unroll
            for (int rt = 0; rt < 4; ++rt)
                a[rt] = *(const f16x8*)(s_xyz + (rt*16 + ln)*32 + kg*8);
            #pragma unroll
            for (int j = 0; j < 4; ++j) {
                const f16x8 bf = *(const f16x8*)(ws + (size_t)(64 + 4*w + j)*1024 + lane*16);
                #pragma unroll
                for (int rt = 0; rt < 4; ++rt)
                    acc[rt][j] = __builtin_amdgcn_mfma_f32_16x16x32_f16(a[rt], bf, acc[rt][j], 0, 0, 0);
            }
        }
        #pragma unroll
        for (int j = 0; j < 4; ++j) {
            const int col = (4*w + j)*16 + ln;
            const float mb = mlp_b[col], g1 = bn1g[col]*INVV, b1 = bn1b[col];
            #pragma unroll
            for (int rt = 0; rt < 4; ++rt)
                #pragma unroll
                for (int r = 0; r < 4; ++r) {
                    const int row = rt*16 + g4 + r;
                    const float h = fmaxf((acc[rt][j][r] + mb)*g1 + b1, 0.f);
                    *(f16*)(s_x + row*512 + swzb(row, col*2)) = (f16)h;
                }
        }
    }
    __syncthreads();

    // ---------- Phase B: Q = X @ WQ (64x64), wave w -> coltile w ------------
    {
        f32x4 accq[4] = {};
        #pragma unroll
        for (int kc = 0; kc < 8; ++kc) {
            const f16x8 bf = *(const f16x8*)(ws + (size_t)(80 + kc*4 + w)*1024 + lane*16);
            #pragma unroll
            for (int rt = 0; rt < 4; ++rt) {
                const int row = rt*16 + ln;
                const f16x8 a = *(const f16x8*)(s_x + row*512 + swzb(row, kc*64 + kg16));
                accq[rt] = __builtin_amdgcn_mfma_f32_16x16x32_f16(a, bf, accq[rt], 0, 0, 0);
            }
        }
        const int col = w*16 + ln;
        #pragma unroll
        for (int rt = 0; rt < 4; ++rt)
            #pragma unroll
            for (int r = 0; r < 4; ++r) {
                const int row = rt*16 + g4 + r;
                *(f16*)(s_q + row*128 + swzb(row, col*2)) = (f16)accq[rt][r];
            }
    }
    __syncthreads();

    // ---------- Phase C: S = Q @ Q^T; reg-softmax with partial exchange -----
    {
        f32x4 accs[4] = {};
        #pragma unroll
        for (int kc = 0; kc < 2; ++kc) {
            const int rowb = w*16 + ln;
            const f16x8 bf = *(const f16x8*)(s_q + rowb*128 + swzb(rowb, kc*64 + kg16));
            #pragma unroll
            for (int rt = 0; rt < 4; ++rt) {
                const int row = rt*16 + ln;
                const f16x8 a = *(const f16x8*)(s_q + row*128 + swzb(row, kc*64 + kg16));
                accs[rt] = __builtin_amdgcn_mfma_f32_16x16x32_f16(a, bf, accs[rt], 0, 0, 0);
            }
        }
        float pm[4][4];
        #pragma unroll
        for (int rt = 0; rt < 4; ++rt)
            #pragma unroll
            for (int r = 0; r < 4; ++r) {
                float v = accs[rt][r];
                float mx = fmaxf(v, __shfl_xor(v, 1));
                mx = fmaxf(mx, __shfl_xor(mx, 2));
                mx = fmaxf(mx, __shfl_xor(mx, 4));
                mx = fmaxf(mx, __shfl_xor(mx, 8));
                pm[rt][r] = mx;
                const float e = __expf(v - mx);
                accs[rt][r] = e;
                float sm = e + __shfl_xor(e, 1);
                sm += __shfl_xor(sm, 2);
                sm += __shfl_xor(sm, 4);
                sm += __shfl_xor(sm, 8);
                if (ln == 0) {
                    const int row = rt*16 + g4 + r;
                    s_part[row*8 + w*2 + 0] = mx;
                    s_part[row*8 + w*2 + 1] = sm;
                }
            }
        __syncthreads();
        const int arow = w*16 + ln;
        #pragma unroll
        for (int rt = 0; rt < 4; ++rt) {
            f16x4v pk;
            #pragma unroll
            for (int r = 0; r < 4; ++r) {
                const int row = rt*16 + g4 + r;
                const f32x4 pa = *(const f32x4*)(s_part + row*8);
                const f32x4 pb = *(const f32x4*)(s_part + row*8 + 4);
                const float fm = fmaxf(fmaxf(pa.x, pa.z), fmaxf(pb.x, pb.z));
                const float den = pa.y*__expf(pa.x - fm) + pa.w*__expf(pa.z - fm)
                                + pb.y*__expf(pb.x - fm) + pb.w*__expf(pb.z - fm);
                const float sc = __expf(pm[rt][r] - fm) / den;
                pk[r] = (f16)(accs[rt][r] * sc);
            }
            *(f16x4v*)(s_q + arow*128 + swzb(arow, (rt*16 + g4)*2)) = pk;
        }
    }
    __syncthreads();

    // ---------- Phase D: per-j {V tile, bounce transpose, XR MFMA} ----------
    f32x4 accr[4][4] = {};
    f32x4 accONE[4] = {};
    {
        f16x8 a2[2][4];
        #pragma unroll
        for (int kc = 0; kc < 2; ++kc)
            #pragma unroll
            for (int rt = 0; rt < 4; ++rt) {
                const int row = rt*16 + ln;
                a2[kc][rt] = *(const f16x8*)(s_q + row*128 + swzb(row, kc*64 + kg16));
            }
        unsigned char* bw = s_m + w*2048;  // per-wave bounce [16 ch][64 samples]
        #pragma unroll
        for (int j = 0; j < 4; ++j) {
            const float vb = v_b[(4*w + j)*16 + ln];
            f32x4 accv[4] = {};
            #pragma unroll 2
            for (int kc = 0; kc < 8; ++kc) {
                const f16x8 bf = *(const f16x8*)(ws + (size_t)(112 + kc*16 + 4*w + j)*1024 + lane*16);
                #pragma unroll
                for (int rt = 0; rt < 4; ++rt) {
                    const int row = rt*16 + ln;
                    const f16x8 a = *(const f16x8*)(s_x + row*512 + swzb(row, kc*64 + kg16));
                    accv[rt] = __builtin_amdgcn_mfma_f32_16x16x32_f16(a, bf, accv[rt], 0, 0, 0);
                }
            }
            #pragma unroll
            for (int rt = 0; rt < 4; ++rt)
                #pragma unroll
                for (int r = 0; r < 4; ++r) {
                    const int sr = rt*16 + g4 + r;
                    *(f16*)(bw + ln*128 + ((sr*2) ^ ((ln & 7) << 4))) = (f16)(accv[rt][r] + vb);
                }
            asm volatile("s_waitcnt lgkmcnt(0)" ::: "memory");
            #pragma unroll
            for (int kc = 0; kc < 2; ++kc) {
                const f16x8 bf = *(const f16x8*)(bw + ln*128 + ((kc*64 + kg16) ^ ((ln & 7) << 4)));
                #pragma unroll
                for (int rt = 0; rt < 4; ++rt)
                    accr[rt][j] = __builtin_amdgcn_mfma_f32_16x16x32_f16(a2[kc][rt], bf, accr[rt][j], 0, 0, 0);
            }
            asm volatile("" ::: "memory");
        }
        // colsum via ones-MFMA (same C/D row layout as accr)
        f16x8 onef;
        #pragma unroll
        for (int i = 0; i < 8; ++i) onef[i] = (f16)1.0f;
        #pragma unroll
        for (int kc = 0; kc < 2; ++kc)
            #pragma unroll
            for (int rt = 0; rt < 4; ++rt)
                accONE[rt] = __builtin_amdgcn_mfma_f32_16x16x32_f16(a2[kc][rt], onef, accONE[rt], 0, 0, 0);
    }
    __syncthreads();  // all waves' X reads done before Y overwrite

    // ---------- D-epilogue: Y = X - XR/colsum (in-place), keep X in regs ----
    f16x4v xsave[4][4];
    #pragma unroll
    for (int j = 0; j < 4; ++j) {
        const int col = (4*w + j)*16 + ln;
        #pragma unroll
        for (int rt = 0; rt < 4; ++rt) {
            f16x4v xs4;
            #pragma unroll
            for (int r = 0; r < 4; ++r) {
                const int row = rt*16 + g4 + r;
                const f16 xv = *(const f16*)(s_x + row*512 + swzb(row, col*2));
                xs4[r] = xv;
                const float yv = (float)xv - accr[rt][j][r] / (1e-9f + accONE[rt][r]);
                *(f16*)(s_x + row*512 + swzb(row, col*2)) = (f16)yv;
            }
            xsave[j][rt] = xs4;
        }
    }
    __syncthreads();

    // ---------- Phase E: T = Y @ WT + t_b; out = maxpool(X + relu(BN2)) -----
    {
        f32x4 acct[4][4] = {};
        #pragma unroll 2
        for (int kc = 0; kc < 8; ++kc) {
            f16x8 a[4];
            #pragma unroll
            for (int rt = 0; rt < 4; ++rt) {
                const int row = rt*16 + ln;
                a[rt] = *(const f16x8*)(s_x + row*512 + swzb(row, kc*64 + kg16));  // Y
            }
            #pragma unroll
            for (int j = 0; j < 4; ++j) {
                const f16x8 bf = *(const f16x8*)(ws + (size_t)(240 + kc*16 + 4*w + j)*1024 + lane*16);
                #pragma unroll
                for (int rt = 0; rt < 4; ++rt)
                    acct[rt][j] = __builtin_amdgcn_mfma_f32_16x16x32_f16(a[rt], bf, acct[rt][j], 0, 0, 0);
            }
        }
        #pragma unroll
        for (int j = 0; j < 4; ++j) {
            const int col = (4*w + j)*16 + ln;
            const float tb = t_b[col], g2 = bn2g[col]*INVV, b2 = bn2b[col];
            float m = -3.4e38f;
            #pragma unroll
            for (int rt = 0; rt < 4; ++rt)
                #pragma unroll
                for (int r = 0; r < 4; ++r) {
                    const float tv = acct[rt][j][r] + tb;
                    const float rl = fmaxf(tv*g2 + b2, 0.f);
                    const float xv = (float)xsave[j][rt][r];
                    m = fmaxf(m, xv + rl);
                }
            m = fmaxf(m, __shfl_xor(m, 16));
            m = fmaxf(m, __shfl_xor(m, 32));
            if (kg == 0)
                out[((size_t)bb*256 + col)*1024 + s] = m;
        }
    }
}

extern "C" void kernel_launch(void* const* d_in, const int* in_sizes, int n_in,
                              void* d_out, int out_size, void* d_ws, size_t ws_size,
                              hipStream_t stream) {
    (void)in_sizes; (void)n_in; (void)out_size; (void)ws_size;
    unsigned char* ws = (unsigned char*)d_ws;
    prep_kernel<<<92 + 314, 256, 0, stream>>>(
        (const float*)d_in[4],   // mlp_w
        (const float*)d_in[8],   // qk_w
        (const float*)d_in[9],   // v_w
        (const float*)d_in[11],  // t_w
        (const float*)d_in[3],   // up_feature
        ws);
    cloudcrop_mfma<<<2048, 256, 0, stream>>>(
        (const float*)d_in[0],   // seed_xyz
        (const float*)d_in[1],   // pointcloud
        (const float*)d_in[2],   // vp_rot
        (const float*)d_in[5],   // mlp_b
        (const float*)d_in[6],   // bn1_g
        (const float*)d_in[7],   // bn1_b
        (const float*)d_in[10],  // v_b
        (const float*)d_in[12],  // t_b
        (const float*)d_in[13],  // bn2_g
        (const float*)d_in[14],  // bn2_b
        ws,
        (float*)d_out);
}